// Round 6
// baseline (146.696 us; speedup 1.0000x reference)
//
#include <hip/hip_runtime.h>
#include <hip/hip_bf16.h>

// Problem constants (fixed-shape problem)
#define KNB    32
#define DEMB   128
#define HIDN   100
#define OUTU   20
#define HHEADS 5
#define OUTW   228   // H*OUT + D = 100 + 128

#define NWAVES 12    // waves per block
#define NITER  3     // nodes per wave (software-pipelined)

typedef __attribute__((ext_vector_type(4))) float f32x4;
typedef __attribute__((ext_vector_type(8))) short bf16x8;

__device__ __forceinline__ unsigned short f2bf(float f) {
    union { float f; unsigned u; } v; v.f = f;
    unsigned r = (v.u + 0x7fffu + ((v.u >> 16) & 1u)) >> 16;
    return (unsigned short)r;
}
__device__ __forceinline__ unsigned pkbf(float lo, float hi) {
    unsigned r;
    asm("v_cvt_pk_bf16_f32 %0, %1, %2" : "=v"(r) : "v"(lo), "v"(hi));
    return r;
}
__device__ __forceinline__ bf16x8 cvt8(float4 a, float4 b) {
    union { unsigned u[4]; bf16x8 v; } t;
    t.u[0] = pkbf(a.x, a.y); t.u[1] = pkbf(a.z, a.w);
    t.u[2] = pkbf(b.x, b.y); t.u[3] = pkbf(b.z, b.w);
    return t.v;
}

// ---------------- prep: FRAGMENT-MAJOR weight layouts ----------------
// W1f[(jt*8+ks)*64 + lane] = 8 bf16 of W1[d][j], j = jt*16+(lane&15), d = ks*32+(lane>>4)*8+e
// W2f[(ks*2+ot)*64 + lane] = 8 bf16 of W2[j][o], o = ot*16+(lane&15), j = ks*32+(lane>>4)*8+e
__global__ void sa_prep(const float* __restrict__ W1, const float* __restrict__ W2,
                        unsigned short* __restrict__ W1f, unsigned short* __restrict__ W2f) {
    int idx = blockIdx.x * 256 + threadIdx.x;          // 32768 total
    if (idx < 28672) {
        int e = idx & 7, lane = (idx >> 3) & 63, ks = (idx >> 9) & 7, jt = idx >> 12;
        int j = jt * 16 + (lane & 15);
        int d = ks * 32 + (lane >> 4) * 8 + e;
        W1f[idx] = (j < HIDN) ? f2bf(W1[d * HIDN + j]) : (unsigned short)0;
    } else {
        int i2 = idx - 28672;                          // < 4096
        int e = i2 & 7, lane = (i2 >> 3) & 63, ot = (i2 >> 9) & 1, ks = i2 >> 10;
        int o = ot * 16 + (lane & 15);
        int jj = ks * 32 + (lane >> 4) * 8 + e;
        W2f[i2] = (o < OUTU && jj < HIDN) ? f2bf(W2[jj * OUTU + o]) : (unsigned short)0;
    }
}

// ---------------- main: 12 waves/block, NITER nodes/wave, cross-node gather prefetch ----------------
// LDS: 57344 (W1f) + 8192 (W2f) + 12*6080 = 138496 B -> 1 block/CU, 12 waves.
__global__ __launch_bounds__(NWAVES * 64, 3)
void sa_main(const float* __restrict__ emb,
             const int* __restrict__ node_idx,
             const int* __restrict__ neigh_idx,
             const float* __restrict__ b1,
             const float* __restrict__ b2,
             const float* __restrict__ Wa,
             const float* __restrict__ ba,
             const unsigned short* __restrict__ W1f,
             const unsigned short* __restrict__ W2f,
             float* __restrict__ out, int nnodes) {
    extern __shared__ char smem[];
    unsigned short* w1_lds = (unsigned short*)smem;                  // 57344 B
    unsigned short* w2_lds = (unsigned short*)(smem + 57344);        // 8192 B (contiguous with W1f)

    const int tid  = threadIdx.x;
    const int lane = tid & 63;
    const int wid  = tid >> 6;
    const int l15 = lane & 15, h4 = lane >> 4;

    char* wbase = smem + 65536 + wid * 6080;
    char* stgB  = wbase;                              // 32 rows x 80 B (bf16 32x32 hid slice)
    float* tT_s = (float*)(wbase + 2560);             // 20*36*4 = 2880 B
    float* pf_s = (float*)(wbase + 2560 + 2880);      // 160*4   = 640 B

    const bf16x8* w1f_v = (const bf16x8*)w1_lds;
    const bf16x8* w2f_v = (const bf16x8*)w2_lds;

    const int node_base = blockIdx.x * (NWAVES * NITER);

    // ---- weight staging loads (oldest in vmem queue) ----
    float4 st[6];
#pragma unroll
    for (int i = 0; i < 6; ++i) {
        int idx = tid + i * (NWAVES * 64);
        if (idx < 4096) st[i] = ((const float4*)W1f)[idx];
    }

    // ---- prologue: prefetch node(it=0)'s neighbor tiles into buf 0 ----
    float4 g0a[2][4], g0c[2][4], g1a[2][4], g1c[2][4];
    {
        int node0 = node_base + wid;
        if (node0 >= nnodes) node0 = nnodes - 1;
        const int* nip = neigh_idx + (size_t)node0 * KNB;
        int q0 = nip[l15], q1 = nip[16 + l15];
        const float* q0p = emb + (size_t)q0 * DEMB + h4 * 8;
        const float* q1p = emb + (size_t)q1 * DEMB + h4 * 8;
#pragma unroll
        for (int ks = 0; ks < 4; ++ks) {
            g0a[0][ks] = *(const float4*)(q0p + ks * 32);
            g0c[0][ks] = *(const float4*)(q0p + ks * 32 + 4);
            g1a[0][ks] = *(const float4*)(q1p + ks * 32);
            g1c[0][ks] = *(const float4*)(q1p + ks * 32 + 4);
        }
    }

    // ---- write staged weights to LDS ----
#pragma unroll
    for (int i = 0; i < 6; ++i) {
        int idx = tid + i * (NWAVES * 64);
        if (idx < 4096) ((float4*)w1_lds)[idx] = st[i];
    }
    __syncthreads();   // the only cross-wave barrier (drains vmem too; buf0 data lands)

#pragma unroll
    for (int it = 0; it < NITER; ++it) {
        const int buf = it & 1;
        int node = node_base + it * NWAVES + wid;
        const int active = (node < nnodes);
        if (node >= nnodes) node = nnodes - 1;

        // ---- node-row loads for CURRENT node (needed at kk>=4, short wait) ----
        const int nid = node_idx[node];
        const float* pn = emb + (size_t)nid * DEMB + h4 * 8;
        float4 gna[4], gnc[4];
#pragma unroll
        for (int ks = 0; ks < 4; ++ks) {
            gna[ks] = *(const float4*)(pn + ks * 32);
            gnc[ks] = *(const float4*)(pn + ks * 32 + 4);
        }
        float4 nodecp;
        if (lane < 32) nodecp = ((const float4*)(emb + (size_t)nid * DEMB))[lane];

        // ---- convert current node's neighbor tiles (data already in flight/arrived) ----
        bf16x8 bf0[4], bf1[4], bnn[4];
#pragma unroll
        for (int ks = 0; ks < 4; ++ks) {
            bf0[ks] = cvt8(g0a[buf][ks], g0c[buf][ks]);
            bf1[ks] = cvt8(g1a[buf][ks], g1c[buf][ks]);
        }

        // ---- PREFETCH next node's neighbor tiles into buf^1 (hidden under fused loop) ----
        if (it + 1 < NITER) {
            int nnode = node_base + (it + 1) * NWAVES + wid;
            if (nnode >= nnodes) nnode = nnodes - 1;
            const int* nip2 = neigh_idx + (size_t)nnode * KNB;
            int q0 = nip2[l15], q1 = nip2[16 + l15];
            const float* q0p = emb + (size_t)q0 * DEMB + h4 * 8;
            const float* q1p = emb + (size_t)q1 * DEMB + h4 * 8;
            const int nb = buf ^ 1;
#pragma unroll
            for (int ks = 0; ks < 4; ++ks) {
                g0a[nb][ks] = *(const float4*)(q0p + ks * 32);
                g0c[nb][ks] = *(const float4*)(q0p + ks * 32 + 4);
                g1a[nb][ks] = *(const float4*)(q1p + ks * 32);
                g1c[nb][ks] = *(const float4*)(q1p + ks * 32 + 4);
            }
        }

        // node-half fragments (waits only the 8 node-row loads)
#pragma unroll
        for (int ks = 0; ks < 4; ++ks) bnn[ks] = cvt8(gna[ks], gnc[ks]);

        __builtin_amdgcn_sched_barrier(0);   // loads above stay above; fused loop stays below

        if (active && lane < 32)
            ((float4*)(out + (size_t)node * OUTW + HHEADS * OUTU))[lane] = nodecp;

        // ---- fused GEMM1 -> GEMM2 over K-slices of 32 hidden units ----
        f32x4 acc2[2][2] = {};
#pragma unroll
        for (int ks = 0; ks < 4; ++ks) {
#pragma unroll
            for (int jt2 = 0; jt2 < 2; ++jt2) {
                const int jt = ks * 2 + jt2;
                const int co = jt2 * 32 + h4 * 8;              // byte col offset in stage row
                if (jt < 7) {
                    f32x4 a0 = {0.f, 0.f, 0.f, 0.f}, a1 = {0.f, 0.f, 0.f, 0.f};
#pragma unroll
                    for (int kk = 0; kk < 8; ++kk) {
                        bf16x8 afr = w1f_v[(jt * 8 + kk) * 64 + lane];
                        bf16x8 bb0 = (kk < 4) ? bf0[kk & 3] : bnn[kk & 3];
                        bf16x8 bb1 = (kk < 4) ? bf1[kk & 3] : bnn[kk & 3];
                        a0 = __builtin_amdgcn_mfma_f32_16x16x32_bf16(afr, bb0, a0, 0, 0, 0);
                        a1 = __builtin_amdgcn_mfma_f32_16x16x32_bf16(afr, bb1, a1, 0, 0, 0);
                    }
                    const int j0 = jt * 16 + h4 * 4;
                    float4 bv;
                    if (j0 + 3 < HIDN) bv = *(const float4*)(b1 + j0);
                    else bv = make_float4(0.f, 0.f, 0.f, 0.f);   // j>=100: acc is 0 there too
                    unsigned u00 = pkbf(fmaxf(a0[0] + bv.x, 0.f), fmaxf(a0[1] + bv.y, 0.f));
                    unsigned u01 = pkbf(fmaxf(a0[2] + bv.z, 0.f), fmaxf(a0[3] + bv.w, 0.f));
                    unsigned u10 = pkbf(fmaxf(a1[0] + bv.x, 0.f), fmaxf(a1[1] + bv.y, 0.f));
                    unsigned u11 = pkbf(fmaxf(a1[2] + bv.z, 0.f), fmaxf(a1[3] + bv.w, 0.f));
                    *(uint2*)(stgB + l15 * 80 + co)        = make_uint2(u00, u01);
                    *(uint2*)(stgB + (16 + l15) * 80 + co) = make_uint2(u10, u11);
                } else {   // jt==7: j in [112,128) -> zeros
                    *(uint2*)(stgB + l15 * 80 + co)        = make_uint2(0u, 0u);
                    *(uint2*)(stgB + (16 + l15) * 80 + co) = make_uint2(0u, 0u);
                }
            }
            // GEMM2 K-step ks
            bf16x8 afr0 = *(const bf16x8*)(stgB + l15 * 80 + h4 * 16);
            bf16x8 afr1 = *(const bf16x8*)(stgB + (16 + l15) * 80 + h4 * 16);
            bf16x8 bfr0 = w2f_v[(ks * 2 + 0) * 64 + lane];
            bf16x8 bfr1 = w2f_v[(ks * 2 + 1) * 64 + lane];
            acc2[0][0] = __builtin_amdgcn_mfma_f32_16x16x32_bf16(afr0, bfr0, acc2[0][0], 0, 0, 0);
            acc2[0][1] = __builtin_amdgcn_mfma_f32_16x16x32_bf16(afr0, bfr1, acc2[0][1], 0, 0, 0);
            acc2[1][0] = __builtin_amdgcn_mfma_f32_16x16x32_bf16(afr1, bfr0, acc2[1][0], 0, 0, 0);
            acc2[1][1] = __builtin_amdgcn_mfma_f32_16x16x32_bf16(afr1, bfr1, acc2[1][1], 0, 0, 0);
        }

        // ---- t = relu(D2 + b2), store transposed tT[o][m] ----
#pragma unroll
        for (int ot = 0; ot < 2; ++ot) {
            int o = ot * 16 + l15;
            if (o < OUTU) {
                float b2v = b2[o];
#pragma unroll
                for (int mt = 0; mt < 2; ++mt) {
                    int m0 = mt * 16 + h4 * 4;
                    f32x4 a = acc2[mt][ot];
                    float4 tv = make_float4(fmaxf(a[0] + b2v, 0.f), fmaxf(a[1] + b2v, 0.f),
                                            fmaxf(a[2] + b2v, 0.f), fmaxf(a[3] + b2v, 0.f));
                    *(float4*)&tT_s[o * 36 + m0] = tv;
                }
            }
        }

        // ---- attention + softmax over heads ----
        {
            int mm = lane & 31;
            float tv[20];
#pragma unroll
            for (int o = 0; o < OUTU; ++o) tv[o] = tT_s[o * 36 + mm];
            float att[5];
#pragma unroll
            for (int h = 0; h < HHEADS; ++h) {
                float s = ba[h];
#pragma unroll
                for (int o = 0; o < OUTU; ++o) s += tv[o] * Wa[o * HHEADS + h];
                att[h] = fmaxf(s, 0.f);
            }
            float mx = att[0];
#pragma unroll
            for (int h = 1; h < HHEADS; ++h) mx = fmaxf(mx, att[h]);
            float e[5], sum = 0.f;
#pragma unroll
            for (int h = 0; h < HHEADS; ++h) { e[h] = __expf(att[h] - mx); sum += e[h]; }
            float inv = 1.f / sum;
            if (lane < 32) {
#pragma unroll
                for (int h = 0; h < HHEADS; ++h) pf_s[mm * HHEADS + h] = e[h] * inv;
            }
        }

        // ---- aggregate: out[n, h*20+o] = sum_k pf[h*32+k] * t[k][o]  (reshape-faithful) ----
#pragma unroll
        for (int pass = 0; pass < 2; ++pass) {
            int idx = pass * 64 + lane;
            if (idx < HHEADS * OUTU && active) {
                int h = idx / OUTU, o = idx % OUTU;
                float s = 0.f;
#pragma unroll
                for (int kk = 0; kk < 8; ++kk) {
                    float4 p4 = *(const float4*)&pf_s[h * 32 + kk * 4];
                    float4 t4 = *(const float4*)&tT_s[o * 36 + kk * 4];
                    s += p4.x * t4.x + p4.y * t4.y + p4.z * t4.z + p4.w * t4.w;
                }
                out[(size_t)node * OUTW + idx] = s;
            }
        }
        // per-wave LDS buffers are private; same-wave RAW handled by lgkmcnt -> no barrier
    }
}

extern "C" void kernel_launch(void* const* d_in, const int* in_sizes, int n_in,
                              void* d_out, int out_size, void* d_ws, size_t ws_size,
                              hipStream_t stream) {
    const float* emb      = (const float*)d_in[0];
    const int*   node_idx = (const int*)d_in[1];
    const int*   neigh_idx= (const int*)d_in[2];
    const float* W1       = (const float*)d_in[3];
    const float* b1       = (const float*)d_in[4];
    const float* W2       = (const float*)d_in[5];
    const float* b2       = (const float*)d_in[6];
    const float* Wa       = (const float*)d_in[7];
    const float* ba       = (const float*)d_in[8];
    float* out = (float*)d_out;

    unsigned short* W1f = (unsigned short*)d_ws;            // 28672 bf16 = 57344 B (frag-major)
    unsigned short* W2f = W1f + 28672;                      // 4096 bf16  =  8192 B (contiguous)

    int n = in_sizes[1];                                    // 20000 nodes
    int smem_bytes = 57344 + 8192 + NWAVES * 6080;          // 138496 B

    static bool attr_set = false;   // idempotent driver attr; not a stream op (graph-safe)
    if (!attr_set) {
        hipFuncSetAttribute((const void*)sa_main,
                            hipFuncAttributeMaxDynamicSharedMemorySize, smem_bytes);
        attr_set = true;
    }

    sa_prep<<<128, 256, 0, stream>>>(W1, W2, W1f, W2f);
    int npb = NWAVES * NITER;                               // 36 nodes per block
    sa_main<<<(n + npb - 1) / npb, NWAVES * 64, smem_bytes, stream>>>(
        emb, node_idx, neigh_idx, b1, b2, Wa, ba, W1f, W2f, out, n);
}

// Round 7
// 104.858 us; speedup vs baseline: 1.3990x; 1.3990x over previous
//
#include <hip/hip_runtime.h>
#include <hip/hip_bf16.h>

// Problem constants (fixed-shape problem)
#define KNB    32
#define DEMB   128
#define HIDN   100
#define OUTU   20
#define HHEADS 5
#define OUTW   228   // H*OUT + D = 100 + 128

#define NWAVES 8     // waves per block, 2 nodes per wave -> 16 nodes/block

typedef __attribute__((ext_vector_type(4))) float f32x4;
typedef __attribute__((ext_vector_type(8))) short bf16x8;

__device__ __forceinline__ unsigned short f2bf(float f) {
    union { float f; unsigned u; } v; v.f = f;
    unsigned r = (v.u + 0x7fffu + ((v.u >> 16) & 1u)) >> 16;
    return (unsigned short)r;
}
__device__ __forceinline__ unsigned pkbf(float lo, float hi) {
    unsigned r;
    asm("v_cvt_pk_bf16_f32 %0, %1, %2" : "=v"(r) : "v"(lo), "v"(hi));
    return r;
}
__device__ __forceinline__ bf16x8 cvt8(float4 a, float4 b) {
    union { unsigned u[4]; bf16x8 v; } t;
    t.u[0] = pkbf(a.x, a.y); t.u[1] = pkbf(a.z, a.w);
    t.u[2] = pkbf(b.x, b.y); t.u[3] = pkbf(b.z, b.w);
    return t.v;
}

// ---------------- prep: FRAGMENT-MAJOR weight layouts ----------------
// W1f[(jt*8+ks)*64 + lane] = 8 bf16 of W1[d][j], j = jt*16+(lane&15), d = ks*32+(lane>>4)*8+e
// W2f[(ks*2+ot)*64 + lane] = 8 bf16 of W2[j][o], o = ot*16+(lane&15), j = ks*32+(lane>>4)*8+e
__global__ void sa_prep(const float* __restrict__ W1, const float* __restrict__ W2,
                        unsigned short* __restrict__ W1f, unsigned short* __restrict__ W2f) {
    int idx = blockIdx.x * 256 + threadIdx.x;          // 32768 total
    if (idx < 28672) {
        int e = idx & 7, lane = (idx >> 3) & 63, ks = (idx >> 9) & 7, jt = idx >> 12;
        int j = jt * 16 + (lane & 15);
        int d = ks * 32 + (lane >> 4) * 8 + e;
        W1f[idx] = (j < HIDN) ? f2bf(W1[d * HIDN + j]) : (unsigned short)0;
    } else {
        int i2 = idx - 28672;                          // < 4096
        int e = i2 & 7, lane = (i2 >> 3) & 63, ot = (i2 >> 9) & 1, ks = i2 >> 10;
        int o = ot * 16 + (lane & 15);
        int jj = ks * 32 + (lane >> 4) * 8 + e;
        W2f[i2] = (o < OUTU && jj < HIDN) ? f2bf(W2[jj * OUTU + o]) : (unsigned short)0;
    }
}

// ---------------- main: 8 waves/block, 2 nodes/wave; each W1 frag read feeds 4 MFMAs ----------------
// LDS: 57344 (W1f) + 8192 (W2f) + 8*12160 (per-wave 2x{stg,tT,pf}) = 162816 B -> 1 block/CU.
__global__ __launch_bounds__(NWAVES * 64, 2)
void sa_main(const float* __restrict__ emb,
             const int* __restrict__ node_idx,
             const int* __restrict__ neigh_idx,
             const float* __restrict__ b1,
             const float* __restrict__ b2,
             const float* __restrict__ Wa,
             const float* __restrict__ ba,
             const unsigned short* __restrict__ W1f,
             const unsigned short* __restrict__ W2f,
             float* __restrict__ out, int nnodes) {
    extern __shared__ char smem[];
    unsigned short* w1_lds = (unsigned short*)smem;                  // 57344 B
    unsigned short* w2_lds = (unsigned short*)(smem + 57344);        // 8192 B (contiguous)

    const int tid  = threadIdx.x;
    const int lane = tid & 63;
    const int wid  = tid >> 6;
    const int l15 = lane & 15, h4 = lane >> 4;
    const int nsel = lane >> 5, ln = lane & 31;      // half-wave node select for epilogue

    char* wbase = smem + 65536 + wid * 12160;
    char*  stg0 = wbase;                              // 32 rows x 80 B
    char*  stg1 = wbase + 2560;
    float* tT0  = (float*)(wbase + 5120);             // 20*36*4 = 2880 B
    float* tT1  = (float*)(wbase + 8000);
    float* pf0  = (float*)(wbase + 10880);            // 160*4
    float* pf1  = (float*)(wbase + 11520);

    const bf16x8* w1f_v = (const bf16x8*)w1_lds;
    const bf16x8* w2f_v = (const bf16x8*)w2_lds;

    const int node0 = blockIdx.x * (NWAVES * 2) + wid * 2;
    const int node1 = node0 + 1;
    const int n0c = node0 < nnodes ? node0 : nnodes - 1;
    const int n1c = node1 < nnodes ? node1 : nnodes - 1;

    // ---- weight staging loads (oldest in vmem queue) ----
    float4 st[8];
#pragma unroll
    for (int i = 0; i < 8; ++i) st[i] = ((const float4*)W1f)[tid + i * 512];  // 4096 = W1f+W2f

    // ---- issue ALL gather loads for BOTH nodes ----
    const int* nip0 = neigh_idx + (size_t)n0c * KNB;
    const int* nip1 = neigh_idx + (size_t)n1c * KNB;
    const int r00 = nip0[l15], r01 = nip0[16 + l15];
    const int r10 = nip1[l15], r11 = nip1[16 + l15];
    const int nid0 = node_idx[n0c], nid1 = node_idx[n1c];
    const float* p00 = emb + (size_t)r00 * DEMB + h4 * 8;
    const float* p01 = emb + (size_t)r01 * DEMB + h4 * 8;
    const float* p10 = emb + (size_t)r10 * DEMB + h4 * 8;
    const float* p11 = emb + (size_t)r11 * DEMB + h4 * 8;
    const float* pn0 = emb + (size_t)nid0 * DEMB + h4 * 8;
    const float* pn1 = emb + (size_t)nid1 * DEMB + h4 * 8;

    float4 A00[4], C00[4], A01[4], C01[4], A10[4], C10[4], A11[4], C11[4];
    float4 AN0[4], CN0[4], AN1[4], CN1[4];
#pragma unroll
    for (int ks = 0; ks < 4; ++ks) {
        A00[ks] = *(const float4*)(p00 + ks * 32); C00[ks] = *(const float4*)(p00 + ks * 32 + 4);
        A01[ks] = *(const float4*)(p01 + ks * 32); C01[ks] = *(const float4*)(p01 + ks * 32 + 4);
        A10[ks] = *(const float4*)(p10 + ks * 32); C10[ks] = *(const float4*)(p10 + ks * 32 + 4);
        A11[ks] = *(const float4*)(p11 + ks * 32); C11[ks] = *(const float4*)(p11 + ks * 32 + 4);
        AN0[ks] = *(const float4*)(pn0 + ks * 32); CN0[ks] = *(const float4*)(pn0 + ks * 32 + 4);
        AN1[ks] = *(const float4*)(pn1 + ks * 32); CN1[ks] = *(const float4*)(pn1 + ks * 32 + 4);
    }
    // node-row output copy: half-wave per node (32 float4 each)
    const int nid_h  = nsel ? nid1 : nid0;
    const int node_h = nsel ? node1 : node0;
    float4 nodecp = ((const float4*)(emb + (size_t)nid_h * DEMB))[ln];

    // ---- write staged weights to LDS ----
#pragma unroll
    for (int i = 0; i < 8; ++i) ((float4*)w1_lds)[tid + i * 512] = st[i];

    // ---- convert gathers to bf16 B-fragments ----
    bf16x8 bf0[4], bf1[4], bnn[4], cf0[4], cf1[4], cnn[4];
#pragma unroll
    for (int ks = 0; ks < 4; ++ks) {
        bf0[ks] = cvt8(A00[ks], C00[ks]);
        bf1[ks] = cvt8(A01[ks], C01[ks]);
        cf0[ks] = cvt8(A10[ks], C10[ks]);
        cf1[ks] = cvt8(A11[ks], C11[ks]);
        bnn[ks] = cvt8(AN0[ks], CN0[ks]);
        cnn[ks] = cvt8(AN1[ks], CN1[ks]);
    }

    __syncthreads();   // the only cross-wave barrier (also drains all vmem)
    __builtin_amdgcn_sched_barrier(0);

    if (node_h < nnodes)
        ((float4*)(out + (size_t)node_h * OUTW + HHEADS * OUTU))[ln] = nodecp;

    // ---- fused GEMM1 -> GEMM2 over K-slices of 32 hidden units, 2 nodes/wave ----
    f32x4 acc20[2][2] = {}, acc21[2][2] = {};
#pragma unroll
    for (int ks = 0; ks < 4; ++ks) {
#pragma unroll
        for (int jt2 = 0; jt2 < 2; ++jt2) {
            const int jt = ks * 2 + jt2;
            const int co = jt2 * 32 + h4 * 8;              // byte col offset in stage row
            if (jt < 7) {
                f32x4 a0 = {0.f,0.f,0.f,0.f}, a1 = {0.f,0.f,0.f,0.f};
                f32x4 b0 = {0.f,0.f,0.f,0.f}, b1v = {0.f,0.f,0.f,0.f};
#pragma unroll
                for (int kk = 0; kk < 8; ++kk) {
                    bf16x8 afr = w1f_v[(jt * 8 + kk) * 64 + lane];   // 1 read -> 4 MFMAs
                    bf16x8 u0 = (kk < 4) ? bf0[kk & 3] : bnn[kk & 3];
                    bf16x8 u1 = (kk < 4) ? bf1[kk & 3] : bnn[kk & 3];
                    bf16x8 v0 = (kk < 4) ? cf0[kk & 3] : cnn[kk & 3];
                    bf16x8 v1 = (kk < 4) ? cf1[kk & 3] : cnn[kk & 3];
                    a0  = __builtin_amdgcn_mfma_f32_16x16x32_bf16(afr, u0, a0, 0, 0, 0);
                    a1  = __builtin_amdgcn_mfma_f32_16x16x32_bf16(afr, u1, a1, 0, 0, 0);
                    b0  = __builtin_amdgcn_mfma_f32_16x16x32_bf16(afr, v0, b0, 0, 0, 0);
                    b1v = __builtin_amdgcn_mfma_f32_16x16x32_bf16(afr, v1, b1v, 0, 0, 0);
                }
                const int j0 = jt * 16 + h4 * 4;
                float4 bv;
                if (j0 + 3 < HIDN) bv = *(const float4*)(b1 + j0);
                else bv = make_float4(0.f, 0.f, 0.f, 0.f);   // j>=100: acc is 0 there too
                *(uint2*)(stg0 + l15 * 80 + co) =
                    make_uint2(pkbf(fmaxf(a0[0] + bv.x, 0.f), fmaxf(a0[1] + bv.y, 0.f)),
                               pkbf(fmaxf(a0[2] + bv.z, 0.f), fmaxf(a0[3] + bv.w, 0.f)));
                *(uint2*)(stg0 + (16 + l15) * 80 + co) =
                    make_uint2(pkbf(fmaxf(a1[0] + bv.x, 0.f), fmaxf(a1[1] + bv.y, 0.f)),
                               pkbf(fmaxf(a1[2] + bv.z, 0.f), fmaxf(a1[3] + bv.w, 0.f)));
                *(uint2*)(stg1 + l15 * 80 + co) =
                    make_uint2(pkbf(fmaxf(b0[0] + bv.x, 0.f), fmaxf(b0[1] + bv.y, 0.f)),
                               pkbf(fmaxf(b0[2] + bv.z, 0.f), fmaxf(b0[3] + bv.w, 0.f)));
                *(uint2*)(stg1 + (16 + l15) * 80 + co) =
                    make_uint2(pkbf(fmaxf(b1v[0] + bv.x, 0.f), fmaxf(b1v[1] + bv.y, 0.f)),
                               pkbf(fmaxf(b1v[2] + bv.z, 0.f), fmaxf(b1v[3] + bv.w, 0.f)));
            } else {   // jt==7: j in [112,128) -> zeros
                *(uint2*)(stg0 + l15 * 80 + co)        = make_uint2(0u, 0u);
                *(uint2*)(stg0 + (16 + l15) * 80 + co) = make_uint2(0u, 0u);
                *(uint2*)(stg1 + l15 * 80 + co)        = make_uint2(0u, 0u);
                *(uint2*)(stg1 + (16 + l15) * 80 + co) = make_uint2(0u, 0u);
            }
        }
        // GEMM2 K-step ks: shared W2 frags feed both nodes
        bf16x8 af00 = *(const bf16x8*)(stg0 + l15 * 80 + h4 * 16);
        bf16x8 af01 = *(const bf16x8*)(stg0 + (16 + l15) * 80 + h4 * 16);
        bf16x8 af10 = *(const bf16x8*)(stg1 + l15 * 80 + h4 * 16);
        bf16x8 af11 = *(const bf16x8*)(stg1 + (16 + l15) * 80 + h4 * 16);
        bf16x8 bfr0 = w2f_v[(ks * 2 + 0) * 64 + lane];
        bf16x8 bfr1 = w2f_v[(ks * 2 + 1) * 64 + lane];
        acc20[0][0] = __builtin_amdgcn_mfma_f32_16x16x32_bf16(af00, bfr0, acc20[0][0], 0, 0, 0);
        acc20[0][1] = __builtin_amdgcn_mfma_f32_16x16x32_bf16(af00, bfr1, acc20[0][1], 0, 0, 0);
        acc20[1][0] = __builtin_amdgcn_mfma_f32_16x16x32_bf16(af01, bfr0, acc20[1][0], 0, 0, 0);
        acc20[1][1] = __builtin_amdgcn_mfma_f32_16x16x32_bf16(af01, bfr1, acc20[1][1], 0, 0, 0);
        acc21[0][0] = __builtin_amdgcn_mfma_f32_16x16x32_bf16(af10, bfr0, acc21[0][0], 0, 0, 0);
        acc21[0][1] = __builtin_amdgcn_mfma_f32_16x16x32_bf16(af10, bfr1, acc21[0][1], 0, 0, 0);
        acc21[1][0] = __builtin_amdgcn_mfma_f32_16x16x32_bf16(af11, bfr0, acc21[1][0], 0, 0, 0);
        acc21[1][1] = __builtin_amdgcn_mfma_f32_16x16x32_bf16(af11, bfr1, acc21[1][1], 0, 0, 0);
    }

    // ---- t = relu(D2 + b2), store transposed tT[o][m], both nodes ----
#pragma unroll
    for (int ot = 0; ot < 2; ++ot) {
        int o = ot * 16 + l15;
        if (o < OUTU) {
            float b2v = b2[o];
#pragma unroll
            for (int mt = 0; mt < 2; ++mt) {
                int m0 = mt * 16 + h4 * 4;
                f32x4 a = acc20[mt][ot];
                *(float4*)&tT0[o * 36 + m0] =
                    make_float4(fmaxf(a[0] + b2v, 0.f), fmaxf(a[1] + b2v, 0.f),
                                fmaxf(a[2] + b2v, 0.f), fmaxf(a[3] + b2v, 0.f));
                f32x4 c = acc21[mt][ot];
                *(float4*)&tT1[o * 36 + m0] =
                    make_float4(fmaxf(c[0] + b2v, 0.f), fmaxf(c[1] + b2v, 0.f),
                                fmaxf(c[2] + b2v, 0.f), fmaxf(c[3] + b2v, 0.f));
            }
        }
    }

    // ---- attention + softmax: HALF-WAVE per node (lanes 0-31 node0, 32-63 node1) ----
    float* tT_h = nsel ? tT1 : tT0;
    float* pf_h = nsel ? pf1 : pf0;
    {
        float tv[20];
#pragma unroll
        for (int o = 0; o < OUTU; ++o) tv[o] = tT_h[o * 36 + ln];
        float att[5];
#pragma unroll
        for (int h = 0; h < HHEADS; ++h) {
            float s = ba[h];                       // uniform -> scalar loads
#pragma unroll
            for (int o = 0; o < OUTU; ++o) s += tv[o] * Wa[o * HHEADS + h];
            att[h] = fmaxf(s, 0.f);
        }
        float mx = att[0];
#pragma unroll
        for (int h = 1; h < HHEADS; ++h) mx = fmaxf(mx, att[h]);
        float e[5], sum = 0.f;
#pragma unroll
        for (int h = 0; h < HHEADS; ++h) { e[h] = __expf(att[h] - mx); sum += e[h]; }
        float inv = 1.f / sum;
#pragma unroll
        for (int h = 0; h < HHEADS; ++h) pf_h[ln * HHEADS + h] = e[h] * inv;
    }

    // ---- aggregate (half-wave): out[n, h*20+o] = sum_k pf[h*32+k] * t[k][o] ----
#pragma unroll
    for (int pass = 0; pass < 4; ++pass) {
        int idx = pass * 32 + ln;
        if (idx < HHEADS * OUTU && node_h < nnodes) {
            int h = idx / OUTU, o = idx % OUTU;
            float s = 0.f;
#pragma unroll
            for (int kk = 0; kk < 8; ++kk) {
                float4 p4 = *(const float4*)&pf_h[h * 32 + kk * 4];
                float4 t4 = *(const float4*)&tT_h[o * 36 + kk * 4];
                s += p4.x * t4.x + p4.y * t4.y + p4.z * t4.z + p4.w * t4.w;
            }
            out[(size_t)node_h * OUTW + idx] = s;
        }
    }
}

extern "C" void kernel_launch(void* const* d_in, const int* in_sizes, int n_in,
                              void* d_out, int out_size, void* d_ws, size_t ws_size,
                              hipStream_t stream) {
    const float* emb      = (const float*)d_in[0];
    const int*   node_idx = (const int*)d_in[1];
    const int*   neigh_idx= (const int*)d_in[2];
    const float* W1       = (const float*)d_in[3];
    const float* b1       = (const float*)d_in[4];
    const float* W2       = (const float*)d_in[5];
    const float* b2       = (const float*)d_in[6];
    const float* Wa       = (const float*)d_in[7];
    const float* ba       = (const float*)d_in[8];
    float* out = (float*)d_out;

    unsigned short* W1f = (unsigned short*)d_ws;            // 28672 bf16 = 57344 B (frag-major)
    unsigned short* W2f = W1f + 28672;                      // 4096 bf16  =  8192 B (contiguous)

    int n = in_sizes[1];                                    // 20000 nodes
    int smem_bytes = 57344 + 8192 + NWAVES * 12160;         // 162816 B

    static bool attr_set = false;   // idempotent driver attr; not a stream op (graph-safe)
    if (!attr_set) {
        hipFuncSetAttribute((const void*)sa_main,
                            hipFuncAttributeMaxDynamicSharedMemorySize, smem_bytes);
        attr_set = true;
    }

    sa_prep<<<128, 256, 0, stream>>>(W1, W2, W1f, W2f);
    int npb = NWAVES * 2;                                   // 16 nodes per block
    sa_main<<<(n + npb - 1) / npb, NWAVES * 64, smem_bytes, stream>>>(
        emb, node_idx, neigh_idx, b1, b2, Wa, ba, W1f, W2f, out, n);
}